// Round 18
// baseline (31.353 us; speedup 1.0000x reference)
//
#include <hip/hip_runtime.h>
#include <hip/hip_bf16.h>

// BernsteinSplineCouplingBlock: BATCH=65536, CHANNELS=64, SPLIT1=SPLIT2=32, DEGREE=10
// out[:, :32] = x[:, :32]
// s = x1 @ W.T + b  -> [B*32, 12]; spline(s, x2) -> out[:, 32:]
// GEMM via split-bf16 (hi+lo) 3-MFMA chain for ~f32 precision.
// R18 = R15 spline (R17 poly softplus reverted: v_log is cheap) + channel-split x4:
//   4096 blocks = 1024 row-groups x 4 channel-quarters, 8 ch/block, ONE packed
//   spline pair per thread. Total MFMA work unchanged (24 disjoint tiles per
//   row-group); per-thread critical path halved; VGPR ~80 -> ~24 waves/CU.

typedef short v8s  __attribute__((ext_vector_type(8)));  // 8 x bf16 (4 VGPRs)
typedef float f32x4 __attribute__((ext_vector_type(4)));
typedef float f32x2 __attribute__((ext_vector_type(2)));

#define LOG2E 1.44269504088896340736f
#define LN2   0.69314718055994530942f
#define SWS   101      // LDS row stride (dwords), odd -> conflict-free reads
#define SWW   1616     // per-wave LDS dwords (16*101)

__device__ __forceinline__ short f2bf(float f) {
    union { float f; unsigned u; } v; v.f = f;
    return (short)((v.u + 0x7FFFu + ((v.u >> 16) & 1u)) >> 16);  // RNE
}

__device__ __forceinline__ float bf2f(short h) {
    union { unsigned u; float f; } v; v.u = ((unsigned)(unsigned short)h) << 16;
    return v.f;
}

__device__ __forceinline__ float sgn01(float x) {
    return (x > 0.f) ? 1.f : ((x < 0.f) ? -1.f : 0.f);
}

// packed f32->bf16 RNE pair (v_cvt_pk_bf16_f32); low short = x, high short = y
__device__ __forceinline__ unsigned pk_bf16_rn(float x, float y) {
    union { __hip_bfloat162 h; unsigned u; } v;
    v.h = __float22bfloat162_rn(make_float2(x, y));
    return v.u;
}
__device__ __forceinline__ float lo_f(unsigned u) {   // low bf16 as f32
    return __uint_as_float(u << 16);
}
__device__ __forceinline__ float hi_f(unsigned u) {   // high bf16 as f32
    return __uint_as_float(u & 0xFFFF0000u);
}

__device__ __forceinline__ float exp2_fast(float x) {
#if __has_builtin(__builtin_amdgcn_exp2f)
    return __builtin_amdgcn_exp2f(x);       // raw v_exp_f32 (2^x)
#else
    return exp2f(x);
#endif
}
__device__ __forceinline__ float log2_fast(float x) {
#if __has_builtin(__builtin_amdgcn_logf)
    return __builtin_amdgcn_logf(x);        // raw v_log_f32 (log2); args >= 1 here
#else
    return __log2f(x);
#endif
}

// ---- packed-pair spline: sv[0..9] raw coeffs, sv[10] width, sv[11] height ----
__device__ __forceinline__ f32x2 spline_horner2(const f32x2* sv, f32x2 xf) {
    const f32x2 zero = {0.f, 0.f};
    const f32x2 one  = {1.f, 1.f};

    f32x2 spv[10], cn_[11];
    cn_[0] = zero;
    f32x2 run = zero;
#pragma unroll
    for (int j = 0; j < 10; ++j) {
        const f32x2 xs = sv[j] * LOG2E;        // v_pk_mul
        f32x2 e;
        e[0] = exp2_fast(xs[0]);
        e[1] = exp2_fast(xs[1]);
        const f32x2 oe = e + 1.0f;             // v_pk_add
        f32x2 l;
        l[0] = log2_fast(oe[0]);
        l[1] = log2_fast(oe[1]);
        spv[j] = l;
        run = run + l;                          // v_pk_add (cumsum)
        cn_[j + 1] = run;
    }
    f32x2 inv;
    inv[0] = __fdividef(1.f, run[0]);
    inv[1] = __fdividef(1.f, run[1]);

    // width: wd = ln2*softplus_l2 + 0.1 (softplus>0 => +0.1)
    const f32x2 xsw = sv[10] * LOG2E;
    f32x2 ew;
    ew[0] = exp2_fast(xsw[0]);
    ew[1] = exp2_fast(xsw[1]);
    const f32x2 oew = ew + 1.0f;
    f32x2 lw;
    lw[0] = log2_fast(oew[0]);
    lw[1] = log2_fast(oew[1]);
    const f32x2 ln2v = {LN2, LN2};
    const f32x2 p1v  = {0.1f, 0.1f};
    const f32x2 wd = __builtin_elementwise_fma(ln2v, lw, p1v);

    f32x2 hg = sv[11];
    hg[0] += copysignf(0.1f, hg[0]);
    hg[1] += copysignf(0.1f, hg[1]);

    f32x2 tq;
    tq[0] = __fdividef(xf[0], wd[0]);
    tq[1] = __fdividef(xf[1], wd[1]);
    const f32x2 t  = tq + 0.5f;
    const f32x2 tc = __builtin_elementwise_min(__builtin_elementwise_max(t, zero), one);
    const f32x2 s  = one - tc;

    // P = sum_{i=1..10} C10_i cn_[i] tc^i s^(10-i); Q = sum C9_i spv[i] tc^i s^(9-i)
    const float C10[11] = {1.f,10.f,45.f,120.f,210.f,252.f,210.f,120.f,45.f,10.f,1.f};
    const float C9[10]  = {1.f,9.f,36.f,84.f,126.f,126.f,84.f,36.f,9.f,1.f};
    f32x2 tk = one, P = zero, Q = zero;
#pragma unroll
    for (int i = 0; i < 10; ++i) {
        Q = __builtin_elementwise_fma(Q, s, tk * (spv[i] * C9[i]));   // pk_fma + 2 pk_mul
        P = __builtin_elementwise_fma(P, s, tk * (cn_[i] * C10[i]));
        tk = tk * tc;                                                  // pk_mul
    }
    P = __builtin_elementwise_fma(P, s, tk * cn_[10]);                 // i=10, C=1

    const f32x2 der = (Q * 10.f) * inv;
    const f32x2 ym  = P * inv;

    f32x2 y;
#pragma unroll
    for (int k = 0; k < 2; ++k) {
        const float yk = (t[k] < 0.f) ? (t[k] * der[k])
                       : ((t[k] > 1.f) ? fmaf(t[k] - 1.f, der[k], 1.f) : ym[k]);
        y[k] = (yk - 0.5f) * hg[k];
    }
    return y;
}

// fallback math (R3-proven de Casteljau)
__device__ __forceinline__ float softplus_f(float x) {
    return __logf(1.0f + __expf(x));
}
__device__ __forceinline__ float spline_eval(const float* sv, float xf) {
    float cn[11];
    cn[0] = 0.f;
    float run = 0.f;
#pragma unroll
    for (int j = 0; j < 10; ++j) { run += softplus_f(sv[j]); cn[j + 1] = run; }
    const float inv = __fdividef(1.f, run);
    const float wd = softplus_f(sv[10]) + 0.1f;
    float hg = sv[11];
    hg += 0.1f * sgn01(hg);
    const float t   = __fdividef(xf, wd) + 0.5f;
    const float tc  = fminf(fmaxf(t, 0.f), 1.f);
#pragma unroll
    for (int n = 10; n >= 2; --n) {
#pragma unroll
        for (int i = 0; i < n; ++i) cn[i] += tc * (cn[i + 1] - cn[i]);
    }
    const float db    = cn[1] - cn[0];
    const float deriv = 10.f * db * inv;
    const float ym    = fmaf(tc, db, cn[0]) * inv;
    float y = (t < 0.f) ? (t * deriv)
            : ((t > 1.f) ? fmaf(t - 1.f, deriv, 1.f) : ym);
    return (y - 0.5f) * hg;
}

// ---- prep: split W f32 -> bf16 hi/lo (RNE both) in B-fragment order ----
// frag layout: [(k>>3)*3072 + out*8 + (k&7)], hi at wsH, lo at wsL
__global__ void prep_w(const float* __restrict__ W, short* __restrict__ wsH,
                       short* __restrict__ wsL) {
    const int g = blockIdx.x * 256 + threadIdx.x;
    if (g < 12288) {
        const int o = g >> 5;        // W row (out index 0..383)
        const int k = g & 31;
        const float w = W[g];
        const short hi = f2bf(w);
        const int off = (k >> 3) * 3072 + o * 8 + (k & 7);
        wsH[off] = hi;
        wsL[off] = f2bf(w - bf2f(hi));
    }
}

// ---- main: 4096 blocks = (row group) x (channel quarter), 4 waves, no barriers ----
// Each block: 64 rows x 8 channels; each thread: ONE packed spline pair.
__global__ __launch_bounds__(256) void bern_spline_fast(
    const float* __restrict__ x, const short* __restrict__ wsH,
    const short* __restrict__ wsL, const float* __restrict__ bias,
    float* __restrict__ out)
{
    __shared__ __align__(16) float sl[4 * SWW];  // per-wave 16 x 101 dwords, 25.9 KB

    const int tid  = threadIdx.x;
    const int wave = tid >> 6;
    const int lane = tid & 63;
    const int cq   = blockIdx.x & 3;            // channel quarter: ch in [cq*8, +8)
    const int block_row = (blockIdx.x >> 2) * 64;

    const int row16 = lane & 15;
    const int kq    = lane >> 4;
    const int arow  = block_row + wave * 16 + row16;

    // xf pair — issued first, consumed deep in spline phase
    const int cg0 = cq * 8 + 2 * kq;            // global channel of spline A
    const f32x2 xf2 = *(const f32x2*)(x + (size_t)arow * 64 + 32 + cg0);

    // A fragment: lane holds x1[row = l&15][k = (l>>4)*8 .. +7], RNE hi+lo split
    const f32x4 a0 = *(const f32x4*)(x + (size_t)arow * 64 + kq * 8);
    const f32x4 a1 = *(const f32x4*)(x + (size_t)arow * 64 + kq * 8 + 4);
    union { v8s v; unsigned u[4]; } AH, AL;
    AH.u[0] = pk_bf16_rn(a0[0], a0[1]);
    AH.u[1] = pk_bf16_rn(a0[2], a0[3]);
    AH.u[2] = pk_bf16_rn(a1[0], a1[1]);
    AH.u[3] = pk_bf16_rn(a1[2], a1[3]);
    AL.u[0] = pk_bf16_rn(a0[0] - lo_f(AH.u[0]), a0[1] - hi_f(AH.u[0]));
    AL.u[1] = pk_bf16_rn(a0[2] - lo_f(AH.u[1]), a0[3] - hi_f(AH.u[1]));
    AL.u[2] = pk_bf16_rn(a1[0] - lo_f(AH.u[2]), a1[1] - hi_f(AH.u[2]));
    AL.u[3] = pk_bf16_rn(a1[2] - lo_f(AH.u[3]), a1[3] - hi_f(AH.u[3]));
    const v8s ah = AH.v, al = AL.v;

    // ---- x1 passthrough directly from A-fragment registers (cq==0 blocks) ----
    if (cq == 0) {
        *(f32x4*)(out + (size_t)arow * 64 + kq * 8)     = a0;
        *(f32x4*)(out + (size_t)arow * 64 + kq * 8 + 4) = a1;
    }

    // bias per C tile: constant along batch-row dim -> MFMA C-in {bv,bv,bv,bv}
    float bv[6];
#pragma unroll
    for (int ot = 0; ot < 6; ++ot)
        bv[ot] = bias[(cq * 6 + ot) * 16 + row16];

    float* swv = sl + wave * SWW;   // wave-private transpose buffer

    // ---- B-frag loads: 6 tiles (outs [cq*96, cq*96+96)) ----
    v8s bh[6], bl[6];
#pragma unroll
    for (int ot = 0; ot < 6; ++ot) {
        const int boff = kq * 3072 + ((cq * 6 + ot) * 16 + row16) * 8;
        bh[ot] = *(const v8s*)(wsH + boff);
        bl[ot] = *(const v8s*)(wsL + boff);
    }

    // ---- MFMA (bias in C) + LDS scatter (stride 101) ----
#pragma unroll
    for (int ot = 0; ot < 6; ++ot) {
        f32x4 cb; cb[0] = bv[ot]; cb[1] = bv[ot]; cb[2] = bv[ot]; cb[3] = bv[ot];
        f32x4 c = __builtin_amdgcn_mfma_f32_16x16x32_bf16(al, bh[ot], cb, 0, 0, 0);
        c = __builtin_amdgcn_mfma_f32_16x16x32_bf16(ah, bl[ot], c, 0, 0, 0);
        c = __builtin_amdgcn_mfma_f32_16x16x32_bf16(ah, bh[ot], c, 0, 0, 0);
#pragma unroll
        for (int r = 0; r < 4; ++r)
            swv[(kq * 4 + r) * SWS + ot * 16 + row16] = c[r];
    }

    // ---- read s-values as {A,B} channel pairs (ds_read2_b32-shaped) ----
    // lane reads batch row row16, local channels 2*kq, 2*kq+1 (24 consecutive f32)
    const float* sp = swv + row16 * SWS + 2 * kq * 12;
    f32x2 s2[12];
#pragma unroll
    for (int j = 0; j < 12; ++j) {
        s2[j][0] = sp[j];
        s2[j][1] = sp[j + 12];
    }

    // ---- packed spline pair + 8B store ----
    const f32x2 y2 = spline_horner2(s2, xf2);
    *(f32x2*)(out + (size_t)arow * 64 + 32 + cg0) = y2;
}

// ---- fallback (R3 structure, known-pass): used only if ws is too small ----
__global__ __launch_bounds__(256) void bern_spline_fallback(
    const float* __restrict__ x, const float* __restrict__ W,
    const float* __restrict__ bias, float* __restrict__ out)
{
    __shared__ short Wh[12288];
    __shared__ short Wl[12288];
    __shared__ float bl[384];
    __shared__ float sl[4 * 16 * 100];

    const int tid  = threadIdx.x;
    const int wave = tid >> 6;
    const int lane = tid & 63;
    const int block_row = blockIdx.x * 64;

    for (int g = tid; g < 12288; g += 256) {
        const int o = g >> 5;
        const int k = g & 31;
        const float w = W[g];
        const short hi = f2bf(w);
        Wh[(k >> 3) * 3072 + o * 8 + (k & 7)] = hi;
        Wl[(k >> 3) * 3072 + o * 8 + (k & 7)] = f2bf(w - bf2f(hi));
    }
    for (int g = tid; g < 384; g += 256) bl[g] = bias[g];
    __syncthreads();

    for (int i = tid; i < 512; i += 256) {
        const int r = i >> 3, q = i & 7;
        *(f32x4*)(out + (size_t)(block_row + r) * 64 + q * 4) =
            *(const f32x4*)(x + (size_t)(block_row + r) * 64 + q * 4);
    }

    const int row16 = lane & 15;
    const int kq    = lane >> 4;
    const int arow  = block_row + wave * 16 + row16;
    const f32x4 a0 = *(const f32x4*)(x + (size_t)arow * 64 + kq * 8);
    const f32x4 a1 = *(const f32x4*)(x + (size_t)arow * 64 + kq * 8 + 4);
    v8s ah, al;
#pragma unroll
    for (int e = 0; e < 4; ++e) {
        const short h0 = f2bf(a0[e]);
        ah[e] = h0;     al[e] = f2bf(a0[e] - bf2f(h0));
        const short h1 = f2bf(a1[e]);
        ah[e + 4] = h1; al[e + 4] = f2bf(a1[e] - bf2f(h1));
    }

    float* swv = sl + wave * 1600;
    const f32x4 zero4 = {0.f, 0.f, 0.f, 0.f};

    for (int qt = 0; qt < 4; ++qt) {
        f32x4 acc[6];
#pragma unroll
        for (int ot = 0; ot < 6; ++ot) {
            const int otg = qt * 6 + ot;
            const int boff = kq * 3072 + (otg * 16 + row16) * 8;
            const v8s bh  = *(const v8s*)(Wh + boff);
            const v8s blo = *(const v8s*)(Wl + boff);
            f32x4 c = __builtin_amdgcn_mfma_f32_16x16x32_bf16(al, bh, zero4, 0, 0, 0);
            c = __builtin_amdgcn_mfma_f32_16x16x32_bf16(ah, blo, c, 0, 0, 0);
            acc[ot] = __builtin_amdgcn_mfma_f32_16x16x32_bf16(ah, bh, c, 0, 0, 0);
        }
#pragma unroll
        for (int ot = 0; ot < 6; ++ot)
#pragma unroll
            for (int r = 0; r < 4; ++r)
                swv[(kq * 4 + r) * 100 + ot * 16 + row16] = acc[ot][r];

#pragma unroll
        for (int p = 0; p < 2; ++p) {
            const int idx = p * 64 + lane;
            const int cl  = idx & 7;
            const int rr  = idx >> 3;
            const int cg  = qt * 8 + cl;

            const float* sp = swv + rr * 100 + cl * 12;
            const f32x4 s0 = *(const f32x4*)(sp);
            const f32x4 s1 = *(const f32x4*)(sp + 4);
            const f32x4 s2 = *(const f32x4*)(sp + 8);
            const f32x4 b0 = *(const f32x4*)(bl + cg * 12);
            const f32x4 b1 = *(const f32x4*)(bl + cg * 12 + 4);
            const f32x4 b2 = *(const f32x4*)(bl + cg * 12 + 8);

            float sv[12];
            sv[0]  = s0[0] + b0[0]; sv[1]  = s0[1] + b0[1];
            sv[2]  = s0[2] + b0[2]; sv[3]  = s0[3] + b0[3];
            sv[4]  = s1[0] + b1[0]; sv[5]  = s1[1] + b1[1];
            sv[6]  = s1[2] + b1[2]; sv[7]  = s1[3] + b1[3];
            sv[8]  = s2[0] + b2[0]; sv[9]  = s2[1] + b2[1];
            sv[10] = s2[2] + b2[2]; sv[11] = s2[3] + b2[3];

            const int rowg = block_row + wave * 16 + rr;
            const float xf = x[(size_t)rowg * 64 + 32 + cg];
            out[(size_t)rowg * 64 + 32 + cg] = spline_eval(sv, xf);
        }
    }
}

extern "C" void kernel_launch(void* const* d_in, const int* in_sizes, int n_in,
                              void* d_out, int out_size, void* d_ws, size_t ws_size,
                              hipStream_t stream) {
    const float* x = (const float*)d_in[0];
    const float* W = (const float*)d_in[1];
    const float* b = (const float*)d_in[2];
    float* out = (float*)d_out;

    if (d_ws != nullptr && ws_size >= 49152) {
        short* wsH = (short*)d_ws;
        short* wsL = wsH + 12288;
        prep_w<<<48, 256, 0, stream>>>(W, wsH, wsL);                     // 48 KB, L2-resident
        bern_spline_fast<<<4096, 256, 0, stream>>>(x, wsH, wsL, b, out); // 64 rows x 8 ch
    } else {
        bern_spline_fallback<<<1024, 256, 0, stream>>>(x, W, b, out);
    }
}

// Round 19
// 28.507 us; speedup vs baseline: 1.0998x; 1.0998x over previous
//
#include <hip/hip_runtime.h>

// BernsteinSplineCouplingBlock: BATCH=65536, CHANNELS=64, SPLIT1=SPLIT2=32, DEGREE=10
// out[:, :32] = x[:, :32]
// s = x1 @ W.T + b  -> [B*32, 12]; spline(s, x2) -> out[:, 32:]
// GEMM via split-bf16 (hi+lo) 3-MFMA chain for ~f32 precision.
// R19 = R13 RESTORED (best measured: 28.43 us). R14-R18 hypothesis sweep all
//   null/negative: occupancy cap (R14), LDS bank fix (R15), in-kernel W split
//   (R16, -8.7us), 1-trans softplus (R17, -1.7us), channel-split x4 (R18, -2.9us).
//   Surviving structure: prep_w + 2048x256 main, R12 pipeline order, packed-f32
//   spline (v_pk_fma), bias folded into MFMA C-in, fused Horner-Bernstein.

typedef short v8s  __attribute__((ext_vector_type(8)));  // 8 x bf16 (4 VGPRs)
typedef float f32x4 __attribute__((ext_vector_type(4)));
typedef float f32x2 __attribute__((ext_vector_type(2)));

#define LOG2E 1.44269504088896340736f
#define LN2   0.69314718055994530942f

__device__ __forceinline__ short f2bf(float f) {
    union { float f; unsigned u; } v; v.f = f;
    return (short)((v.u + 0x7FFFu + ((v.u >> 16) & 1u)) >> 16);  // RNE
}

__device__ __forceinline__ float bf2f(short h) {
    union { unsigned u; float f; } v; v.u = ((unsigned)(unsigned short)h) << 16;
    return v.f;
}

__device__ __forceinline__ float sgn01(float x) {
    return (x > 0.f) ? 1.f : ((x < 0.f) ? -1.f : 0.f);
}

__device__ __forceinline__ float exp2_fast(float x) {
#if __has_builtin(__builtin_amdgcn_exp2f)
    return __builtin_amdgcn_exp2f(x);       // raw v_exp_f32 (2^x)
#else
    return exp2f(x);
#endif
}
__device__ __forceinline__ float log2_fast(float x) {
#if __has_builtin(__builtin_amdgcn_logf)
    return __builtin_amdgcn_logf(x);        // raw v_log_f32 (log2); args >= 1 here
#else
    return __log2f(x);
#endif
}

// ---- packed-pair spline: sv[0..9] raw coeffs, sv[10] width, sv[11] height ----
__device__ __forceinline__ f32x2 spline_horner2(const f32x2* sv, f32x2 xf) {
    const f32x2 zero = {0.f, 0.f};
    const f32x2 one  = {1.f, 1.f};

    f32x2 spv[10], cn_[11];
    cn_[0] = zero;
    f32x2 run = zero;
#pragma unroll
    for (int j = 0; j < 10; ++j) {
        const f32x2 xs = sv[j] * LOG2E;        // v_pk_mul
        f32x2 e;
        e[0] = exp2_fast(xs[0]);
        e[1] = exp2_fast(xs[1]);
        const f32x2 oe = e + 1.0f;             // v_pk_add
        f32x2 l;
        l[0] = log2_fast(oe[0]);
        l[1] = log2_fast(oe[1]);
        spv[j] = l;
        run = run + l;                          // v_pk_add (cumsum)
        cn_[j + 1] = run;
    }
    f32x2 inv;
    inv[0] = __fdividef(1.f, run[0]);
    inv[1] = __fdividef(1.f, run[1]);

    // width: wd = ln2*softplus_l2 + 0.1 (softplus>0 => +0.1)
    const f32x2 xsw = sv[10] * LOG2E;
    f32x2 ew;
    ew[0] = exp2_fast(xsw[0]);
    ew[1] = exp2_fast(xsw[1]);
    const f32x2 oew = ew + 1.0f;
    f32x2 lw;
    lw[0] = log2_fast(oew[0]);
    lw[1] = log2_fast(oew[1]);
    const f32x2 ln2v = {LN2, LN2};
    const f32x2 p1v  = {0.1f, 0.1f};
    const f32x2 wd = __builtin_elementwise_fma(ln2v, lw, p1v);

    f32x2 hg = sv[11];
    hg[0] += copysignf(0.1f, hg[0]);
    hg[1] += copysignf(0.1f, hg[1]);

    f32x2 tq;
    tq[0] = __fdividef(xf[0], wd[0]);
    tq[1] = __fdividef(xf[1], wd[1]);
    const f32x2 t  = tq + 0.5f;
    const f32x2 tc = __builtin_elementwise_min(__builtin_elementwise_max(t, zero), one);
    const f32x2 s  = one - tc;

    // P = sum_{i=1..10} C10_i cn_[i] tc^i s^(10-i); Q = sum C9_i spv[i] tc^i s^(9-i)
    const float C10[11] = {1.f,10.f,45.f,120.f,210.f,252.f,210.f,120.f,45.f,10.f,1.f};
    const float C9[10]  = {1.f,9.f,36.f,84.f,126.f,126.f,84.f,36.f,9.f,1.f};
    f32x2 tk = one, P = zero, Q = zero;
#pragma unroll
    for (int i = 0; i < 10; ++i) {
        Q = __builtin_elementwise_fma(Q, s, tk * (spv[i] * C9[i]));   // pk_fma + 2 pk_mul
        P = __builtin_elementwise_fma(P, s, tk * (cn_[i] * C10[i]));
        tk = tk * tc;                                                  // pk_mul
    }
    P = __builtin_elementwise_fma(P, s, tk * cn_[10]);                 // i=10, C=1

    const f32x2 der = (Q * 10.f) * inv;
    const f32x2 ym  = P * inv;

    f32x2 y;
#pragma unroll
    for (int k = 0; k < 2; ++k) {
        const float yk = (t[k] < 0.f) ? (t[k] * der[k])
                       : ((t[k] > 1.f) ? fmaf(t[k] - 1.f, der[k], 1.f) : ym[k]);
        y[k] = (yk - 0.5f) * hg[k];
    }
    return y;
}

// fallback math (R3-proven de Casteljau)
__device__ __forceinline__ float softplus_f(float x) {
    return __logf(1.0f + __expf(x));
}
__device__ __forceinline__ float spline_eval(const float* sv, float xf) {
    float cn[11];
    cn[0] = 0.f;
    float run = 0.f;
#pragma unroll
    for (int j = 0; j < 10; ++j) { run += softplus_f(sv[j]); cn[j + 1] = run; }
    const float inv = __fdividef(1.f, run);
    const float wd = softplus_f(sv[10]) + 0.1f;
    float hg = sv[11];
    hg += 0.1f * sgn01(hg);
    const float t   = __fdividef(xf, wd) + 0.5f;
    const float tc  = fminf(fmaxf(t, 0.f), 1.f);
#pragma unroll
    for (int n = 10; n >= 2; --n) {
#pragma unroll
        for (int i = 0; i < n; ++i) cn[i] += tc * (cn[i + 1] - cn[i]);
    }
    const float db    = cn[1] - cn[0];
    const float deriv = 10.f * db * inv;
    const float ym    = fmaf(tc, db, cn[0]) * inv;
    float y = (t < 0.f) ? (t * deriv)
            : ((t > 1.f) ? fmaf(t - 1.f, deriv, 1.f) : ym);
    return (y - 0.5f) * hg;
}

// ---- prep: split W f32 -> bf16 hi/lo (RNE both) in B-fragment order ----
// frag layout: [(k>>3)*3072 + out*8 + (k&7)], hi at wsH, lo at wsL
__global__ void prep_w(const float* __restrict__ W, short* __restrict__ wsH,
                       short* __restrict__ wsL) {
    const int g = blockIdx.x * 256 + threadIdx.x;
    if (g < 12288) {
        const int o = g >> 5;        // W row (out index 0..383)
        const int k = g & 31;
        const float w = W[g];
        const short hi = f2bf(w);
        const int off = (k >> 3) * 3072 + o * 8 + (k & 7);
        wsH[off] = hi;
        wsL[off] = f2bf(w - bf2f(hi));
    }
}

// ---- main: 2048 blocks = (row group) x (channel half), 4 waves, no barriers ----
__global__ __launch_bounds__(256) void bern_spline_fast(
    const float* __restrict__ x, const short* __restrict__ wsH,
    const short* __restrict__ wsL, const float* __restrict__ bias,
    float* __restrict__ out)
{
    __shared__ __align__(16) float sl[4 * 16 * 100];  // per-wave 16x(96+4pad), 25.6 KB

    const int tid  = threadIdx.x;
    const int wave = tid >> 6;
    const int lane = tid & 63;
    const int cbit = blockIdx.x & 1;            // channel half: ch in [cbit*16, +16)
    const int block_row = (blockIdx.x >> 1) * 64;

    const int row16 = lane & 15;
    const int kq    = lane >> 4;
    const int arow  = block_row + wave * 16 + row16;

    // xf pairs for both halves — issued first, consumed deep in spline phase
    const int cg0_h0 = cbit * 16 + 2 * kq;
    const f32x2 xf2_0 = *(const f32x2*)(x + (size_t)arow * 64 + 32 + cg0_h0);
    const f32x2 xf2_1 = *(const f32x2*)(x + (size_t)arow * 64 + 32 + cg0_h0 + 8);

    // A fragment: lane holds x1[row = l&15][k = (l>>4)*8 .. +7], RNE hi+lo split
    const f32x4 a0 = *(const f32x4*)(x + (size_t)arow * 64 + kq * 8);
    const f32x4 a1 = *(const f32x4*)(x + (size_t)arow * 64 + kq * 8 + 4);
    v8s ah, al;
#pragma unroll
    for (int e = 0; e < 4; ++e) {
        const short h0 = f2bf(a0[e]);
        ah[e] = h0;     al[e] = f2bf(a0[e] - bf2f(h0));
        const short h1 = f2bf(a1[e]);
        ah[e + 4] = h1; al[e + 4] = f2bf(a1[e] - bf2f(h1));
    }

    // ---- x1 passthrough directly from A-fragment registers (even blocks) ----
    if (cbit == 0) {
        *(f32x4*)(out + (size_t)arow * 64 + kq * 8)     = a0;
        *(f32x4*)(out + (size_t)arow * 64 + kq * 8 + 4) = a1;
    }

    // bias per C tile: constant along batch-row dim -> MFMA C-in {bv,bv,bv,bv}
    float bv0[6], bv1[6];
#pragma unroll
    for (int ot = 0; ot < 6; ++ot) {
        bv0[ot] = bias[(cbit * 12 + ot) * 16 + row16];
        bv1[ot] = bias[(cbit * 12 + 6 + ot) * 16 + row16];
    }

    float* swv = sl + wave * 1600;   // wave-private transpose buffer

    // ---- B-frag loads, BOTH halves up front (L2 latency overlapped) ----
    v8s bh0[6], bl0[6], bh1[6], bl1[6];
#pragma unroll
    for (int ot = 0; ot < 6; ++ot) {
        const int boff0 = kq * 3072 + ((cbit * 12 + ot) * 16 + row16) * 8;
        const int boff1 = kq * 3072 + ((cbit * 12 + 6 + ot) * 16 + row16) * 8;
        bh0[ot] = *(const v8s*)(wsH + boff0);
        bl0[ot] = *(const v8s*)(wsL + boff0);
        bh1[ot] = *(const v8s*)(wsH + boff1);
        bl1[ot] = *(const v8s*)(wsL + boff1);
    }

    // ---- MFMA half 0 (bias in C) + LDS scatter ----
#pragma unroll
    for (int ot = 0; ot < 6; ++ot) {
        f32x4 cb; cb[0] = bv0[ot]; cb[1] = bv0[ot]; cb[2] = bv0[ot]; cb[3] = bv0[ot];
        f32x4 c = __builtin_amdgcn_mfma_f32_16x16x32_bf16(al, bh0[ot], cb, 0, 0, 0);
        c = __builtin_amdgcn_mfma_f32_16x16x32_bf16(ah, bl0[ot], c, 0, 0, 0);
        c = __builtin_amdgcn_mfma_f32_16x16x32_bf16(ah, bh0[ot], c, 0, 0, 0);
#pragma unroll
        for (int r = 0; r < 4; ++r)
            swv[(kq * 4 + r) * 100 + ot * 16 + row16] = c[r];
    }

    // ---- read sv0 into registers (the one exposed LDS round trip) ----
    const float* sp = swv + row16 * 100 + 2 * kq * 12;
    const f32x4 vA00 = *(const f32x4*)(sp);
    const f32x4 vA01 = *(const f32x4*)(sp + 4);
    const f32x4 vA02 = *(const f32x4*)(sp + 8);
    const f32x4 vB00 = *(const f32x4*)(sp + 12);
    const f32x4 vB01 = *(const f32x4*)(sp + 16);
    const f32x4 vB02 = *(const f32x4*)(sp + 20);

    // ---- MFMA half 1 into registers (no LDS touch -> legal before spline0) ----
    f32x4 c10, c11, c12, c13, c14, c15;
    {
        f32x4 cb;
#define MFMA_H1(CC, OT) \
        cb[0] = bv1[OT]; cb[1] = bv1[OT]; cb[2] = bv1[OT]; cb[3] = bv1[OT]; \
        CC = __builtin_amdgcn_mfma_f32_16x16x32_bf16(al, bh1[OT], cb, 0, 0, 0); \
        CC = __builtin_amdgcn_mfma_f32_16x16x32_bf16(ah, bl1[OT], CC, 0, 0, 0); \
        CC = __builtin_amdgcn_mfma_f32_16x16x32_bf16(ah, bh1[OT], CC, 0, 0, 0);
        MFMA_H1(c10, 0) MFMA_H1(c11, 1) MFMA_H1(c12, 2)
        MFMA_H1(c13, 3) MFMA_H1(c14, 4) MFMA_H1(c15, 5)
#undef MFMA_H1
    }

    // ---- write1 (after sv0 is safely in regs) ----
#pragma unroll
    for (int r = 0; r < 4; ++r) {
        swv[(kq * 4 + r) * 100 +  0 + row16] = c10[r];
        swv[(kq * 4 + r) * 100 + 16 + row16] = c11[r];
        swv[(kq * 4 + r) * 100 + 32 + row16] = c12[r];
        swv[(kq * 4 + r) * 100 + 48 + row16] = c13[r];
        swv[(kq * 4 + r) * 100 + 64 + row16] = c14[r];
        swv[(kq * 4 + r) * 100 + 80 + row16] = c15[r];
    }

    // ---- issue sv1 reads; latency hides under spline0's VALU chain ----
    const f32x4 vA10 = *(const f32x4*)(sp);
    const f32x4 vA11 = *(const f32x4*)(sp + 4);
    const f32x4 vA12 = *(const f32x4*)(sp + 8);
    const f32x4 vB10 = *(const f32x4*)(sp + 12);
    const f32x4 vB11 = *(const f32x4*)(sp + 16);
    const f32x4 vB12 = *(const f32x4*)(sp + 20);

    // ---- spline half 0 (packed A,B pair) ----
    {
        f32x2 sv2[12];
#pragma unroll
        for (int e = 0; e < 4; ++e) {
            sv2[e][0]     = vA00[e]; sv2[e][1]     = vB00[e];
            sv2[e + 4][0] = vA01[e]; sv2[e + 4][1] = vB01[e];
            sv2[e + 8][0] = vA02[e]; sv2[e + 8][1] = vB02[e];
        }
        const f32x2 y2 = spline_horner2(sv2, xf2_0);
        *(f32x2*)(out + (size_t)arow * 64 + 32 + cg0_h0) = y2;
    }

    // ---- spline half 1 (packed A,B pair) ----
    {
        f32x2 sv2[12];
#pragma unroll
        for (int e = 0; e < 4; ++e) {
            sv2[e][0]     = vA10[e]; sv2[e][1]     = vB10[e];
            sv2[e + 4][0] = vA11[e]; sv2[e + 4][1] = vB11[e];
            sv2[e + 8][0] = vA12[e]; sv2[e + 8][1] = vB12[e];
        }
        const f32x2 y2 = spline_horner2(sv2, xf2_1);
        *(f32x2*)(out + (size_t)arow * 64 + 32 + cg0_h0 + 8) = y2;
    }
}

// ---- fallback (R3 structure, known-pass): used only if ws is too small ----
__global__ __launch_bounds__(256) void bern_spline_fallback(
    const float* __restrict__ x, const float* __restrict__ W,
    const float* __restrict__ bias, float* __restrict__ out)
{
    __shared__ short Wh[12288];
    __shared__ short Wl[12288];
    __shared__ float bl[384];
    __shared__ float sl[4 * 16 * 100];

    const int tid  = threadIdx.x;
    const int wave = tid >> 6;
    const int lane = tid & 63;
    const int block_row = blockIdx.x * 64;

    for (int g = tid; g < 12288; g += 256) {
        const int o = g >> 5;
        const int k = g & 31;
        const float w = W[g];
        const short hi = f2bf(w);
        Wh[(k >> 3) * 3072 + o * 8 + (k & 7)] = hi;
        Wl[(k >> 3) * 3072 + o * 8 + (k & 7)] = f2bf(w - bf2f(hi));
    }
    for (int g = tid; g < 384; g += 256) bl[g] = bias[g];
    __syncthreads();

    for (int i = tid; i < 512; i += 256) {
        const int r = i >> 3, q = i & 7;
        *(f32x4*)(out + (size_t)(block_row + r) * 64 + q * 4) =
            *(const f32x4*)(x + (size_t)(block_row + r) * 64 + q * 4);
    }

    const int row16 = lane & 15;
    const int kq    = lane >> 4;
    const int arow  = block_row + wave * 16 + row16;
    const f32x4 a0 = *(const f32x4*)(x + (size_t)arow * 64 + kq * 8);
    const f32x4 a1 = *(const f32x4*)(x + (size_t)arow * 64 + kq * 8 + 4);
    v8s ah, al;
#pragma unroll
    for (int e = 0; e < 4; ++e) {
        const short h0 = f2bf(a0[e]);
        ah[e] = h0;     al[e] = f2bf(a0[e] - bf2f(h0));
        const short h1 = f2bf(a1[e]);
        ah[e + 4] = h1; al[e + 4] = f2bf(a1[e] - bf2f(h1));
    }

    float* swv = sl + wave * 1600;
    const f32x4 zero4 = {0.f, 0.f, 0.f, 0.f};

    for (int qt = 0; qt < 4; ++qt) {
        f32x4 acc[6];
#pragma unroll
        for (int ot = 0; ot < 6; ++ot) {
            const int otg = qt * 6 + ot;
            const int boff = kq * 3072 + (otg * 16 + row16) * 8;
            const v8s bh  = *(const v8s*)(Wh + boff);
            const v8s blo = *(const v8s*)(Wl + boff);
            f32x4 c = __builtin_amdgcn_mfma_f32_16x16x32_bf16(al, bh, zero4, 0, 0, 0);
            c = __builtin_amdgcn_mfma_f32_16x16x32_bf16(ah, blo, c, 0, 0, 0);
            acc[ot] = __builtin_amdgcn_mfma_f32_16x16x32_bf16(ah, bh, c, 0, 0, 0);
        }
#pragma unroll
        for (int ot = 0; ot < 6; ++ot)
#pragma unroll
            for (int r = 0; r < 4; ++r)
                swv[(kq * 4 + r) * 100 + ot * 16 + row16] = acc[ot][r];

#pragma unroll
        for (int p = 0; p < 2; ++p) {
            const int idx = p * 64 + lane;
            const int cl  = idx & 7;
            const int rr  = idx >> 3;
            const int cg  = qt * 8 + cl;

            const float* sp = swv + rr * 100 + cl * 12;
            const f32x4 s0 = *(const f32x4*)(sp);
            const f32x4 s1 = *(const f32x4*)(sp + 4);
            const f32x4 s2 = *(const f32x4*)(sp + 8);
            const f32x4 b0 = *(const f32x4*)(bl + cg * 12);
            const f32x4 b1 = *(const f32x4*)(bl + cg * 12 + 4);
            const f32x4 b2 = *(const f32x4*)(bl + cg * 12 + 8);

            float sv[12];
            sv[0]  = s0[0] + b0[0]; sv[1]  = s0[1] + b0[1];
            sv[2]  = s0[2] + b0[2]; sv[3]  = s0[3] + b0[3];
            sv[4]  = s1[0] + b1[0]; sv[5]  = s1[1] + b1[1];
            sv[6]  = s1[2] + b1[2]; sv[7]  = s1[3] + b1[3];
            sv[8]  = s2[0] + b2[0]; sv[9]  = s2[1] + b2[1];
            sv[10] = s2[2] + b2[2]; sv[11] = s2[3] + b2[3];

            const int rowg = block_row + wave * 16 + rr;
            const float xf = x[(size_t)rowg * 64 + 32 + cg];
            out[(size_t)rowg * 64 + 32 + cg] = spline_eval(sv, xf);
        }
    }
}

extern "C" void kernel_launch(void* const* d_in, const int* in_sizes, int n_in,
                              void* d_out, int out_size, void* d_ws, size_t ws_size,
                              hipStream_t stream) {
    const float* x = (const float*)d_in[0];
    const float* W = (const float*)d_in[1];
    const float* b = (const float*)d_in[2];
    float* out = (float*)d_out;

    if (d_ws != nullptr && ws_size >= 49152) {
        short* wsH = (short*)d_ws;
        short* wsL = wsH + 12288;
        prep_w<<<48, 256, 0, stream>>>(W, wsH, wsL);                     // 48 KB, L2-resident
        bern_spline_fast<<<2048, 256, 0, stream>>>(x, wsH, wsL, b, out); // 64 rows x 16 ch
    } else {
        bern_spline_fallback<<<1024, 256, 0, stream>>>(x, W, b, out);
    }
}